// Round 13
// baseline (1364.149 us; speedup 1.0000x reference)
//
#include <hip/hip_runtime.h>
#include <math.h>

#define SEQ 512
#define HID 512
#define NGROUP 8              // batch groups of 16; group g = bid & 7
#define GB 16                 // batches per group
#define BPG 32                // blocks per group (each owns 16 n-cols)
#define SLOTU 65536           // ushorts per H slot ([g][b16][k512] bf16)
#define GSLOTU 8192           // ushorts per group per slot (16 KB)
#define LROW 520              // LDS row stride in ushorts (512 + 8 pad -> balanced banks)
// ws layout: [0, 256 KB) two bf16 H slots | [256 KB, +2 KB) flags (8 groups * 64 ints)

typedef __attribute__((ext_vector_type(8))) short short8;   // 8 bf16 = 4 VGPRs (MFMA A/B)
typedef __attribute__((ext_vector_type(4))) float floatx4;  // MFMA C/D

__device__ __forceinline__ unsigned short f2bf(float f) {   // RNE fp32->bf16
    unsigned u = __builtin_bit_cast(unsigned, f);
    return (unsigned short)((u + 0x7FFFu + ((u >> 16) & 1u)) >> 16);
}
__device__ __forceinline__ float bf2f(unsigned short h) {
    unsigned u = ((unsigned)h) << 16;
    return __builtin_bit_cast(float, u);
}
__device__ __forceinline__ float fast_sigmoid(float x) {
    return 1.0f / (1.0f + __expf(-x));
}
__device__ __forceinline__ float fast_tanh(float x) {       // stable for |x| large
    float e = __expf(-2.0f * fabsf(x));
    float t = (1.0f - e) / (1.0f + e);
    return x < 0.0f ? -t : t;
}

__global__ void lstm_init(const float* __restrict__ H0, unsigned short* __restrict__ hb) {
    int idx = blockIdx.x * blockDim.x + threadIdx.x;
    if (idx < SLOTU) {
        int k = idx & 511, b = (idx >> 9) & 15, g = idx >> 13;
        hb[idx] = f2bf(H0[(g * GB + b) * HID + k]);       // slot0 = H(t=0)
    } else if (idx < SLOTU + NGROUP * 64) {
        ((int*)(hb + 2 * SLOTU))[idx - SLOTU] = 0;        // flags = 0
    }
}

__global__ __launch_bounds__(256, 1)
void lstm_main(const float* __restrict__ x,
               const float* __restrict__ C0,
               const float* __restrict__ Wi, const float* __restrict__ bi,
               const float* __restrict__ Wf, const float* __restrict__ bf_,
               const float* __restrict__ Wc, const float* __restrict__ bc,
               const float* __restrict__ Wo, const float* __restrict__ bo,
               float* __restrict__ out, unsigned short* __restrict__ hb) {
    int* flags = (int*)(hb + 2 * SLOTU);

    const int bid  = blockIdx.x;
    const int g    = bid & 7;
    const int cb   = bid >> 3;
    const int tid  = threadIdx.x;
    const int w    = tid >> 6;          // wave 0..3 (owns cols cb*16+w*4 .. +3)
    const int lane = tid & 63;
    const int q    = lane >> 4;         // quad
    const int c    = lane & 15;         // low lane bits

    // MFMA index roles (m89/m91/m120-verified layouts):
    //   A-frag: lane holds A[m = lane&15][k = quad*8+j]   (m = col_local*4 + gate)
    //   B-frag: lane holds B[k = quad*8+j][n = lane&15]   (n = batch)
    //   D:      lane holds D[m = quad*4+r][n = lane&15]   (r = gate, col_local = quad)
    const int gate = c & 3;                       // for A-frag build
    const int colA = cb * 16 + w * 4 + (c >> 2);  // A-frag column
    const int colD = cb * 16 + w * 4 + q;         // this lane's output column
    const int bD   = g * GB + c;                  // this lane's batch

    // ---- A-fragments: hi+lo bf16 split of W, step-invariant, in registers ----
    const float* Wg = (gate == 0) ? Wi : (gate == 1) ? Wf : (gate == 2) ? Wc : Wo;
    short8 aHi[16], aLo[16];
    #pragma unroll
    for (int kt = 0; kt < 16; ++kt) {
        #pragma unroll
        for (int j = 0; j < 8; ++j) {
            int k = kt * 32 + q * 8 + j;
            float wv = Wg[(k + 1) * HID + colA];   // rows 1..512 are H weights
            unsigned short hi = f2bf(wv);
            unsigned short lo = f2bf(wv - bf2f(hi));
            aHi[kt][j] = (short)hi;
            aLo[kt][j] = (short)lo;
        }
    }

    // epilogue constants (row 0 = x weight, bias) + C state, all for (colD, bD)
    const float biasI = bi[colD], biasF = bf_[colD], biasC = bc[colD], biasO = bo[colD];
    const float w0I = Wi[colD], w0F = Wf[colD], w0C = Wc[colD], w0O = Wo[colD];
    float Cst = C0[bD * HID + colD];
    const float* xrow = x + bD * SEQ;

    __shared__ unsigned short hlds[16 * LROW];   // 16.6 KB staged H tile [b][k] bf16

    int* myflag = flags + g * 64 + cb;

    for (int t = 0; t < SEQ; ++t) {
        // ---- wait for all 32 producer flags of this group. No s_sleep: the
        //      dependent load->cmp->branch loop self-throttles at ~1 fabric RT
        //      per retry; removing the sleep cuts discovery quantization. ----
        if (tid < BPG) {
            const int* fp = flags + g * 64 + tid;
            while (__hip_atomic_load(fp, __ATOMIC_RELAXED, __HIP_MEMORY_SCOPE_AGENT) < t)
                ;
        }
        __syncthreads();

        // ---- stage 16 KB H_t tile: 64 B/thread, coherent dwordx4 burst ----
        {
            const unsigned short* gsrc = hb + (t & 1) * SLOTU + g * GSLOTU + tid * 32;
            float4 v0, v1, v2, v3;
            asm volatile(
                "global_load_dwordx4 %0, %4, off sc0 sc1\n\t"
                "global_load_dwordx4 %1, %4, off offset:16 sc0 sc1\n\t"
                "global_load_dwordx4 %2, %4, off offset:32 sc0 sc1\n\t"
                "global_load_dwordx4 %3, %4, off offset:48 sc0 sc1\n\t"
                "s_waitcnt vmcnt(0)"
                : "=&v"(v0), "=&v"(v1), "=&v"(v2), "=&v"(v3)
                : "v"(gsrc) : "memory");
            int b = tid >> 4, ch = tid & 15;
            unsigned short* dst = hlds + b * LROW + ch * 32;
            *(float4*)(dst + 0)  = v0;
            *(float4*)(dst + 8)  = v1;
            *(float4*)(dst + 16) = v2;
            *(float4*)(dst + 24) = v3;
        }
        __syncthreads();

        // ---- GEMM: D[64x16] = W^T (hi+lo) x H, 16 K-tiles, A in regs, B from LDS.
        //      4 independent accumulator chains (proven r12: -32 us vs single). ----
        floatx4 a0 = {0.f, 0.f, 0.f, 0.f}, a1 = a0, a2 = a0, a3 = a0;
        const unsigned short* brow = hlds + c * LROW + q * 8;
        #pragma unroll
        for (int kt = 0; kt < 16; kt += 4) {
            short8 b0 = *(const short8*)(brow + (kt + 0) * 32);
            a0 = __builtin_amdgcn_mfma_f32_16x16x32_bf16(aHi[kt + 0], b0, a0, 0, 0, 0);
            a0 = __builtin_amdgcn_mfma_f32_16x16x32_bf16(aLo[kt + 0], b0, a0, 0, 0, 0);
            short8 b1 = *(const short8*)(brow + (kt + 1) * 32);
            a1 = __builtin_amdgcn_mfma_f32_16x16x32_bf16(aHi[kt + 1], b1, a1, 0, 0, 0);
            a1 = __builtin_amdgcn_mfma_f32_16x16x32_bf16(aLo[kt + 1], b1, a1, 0, 0, 0);
            short8 b2 = *(const short8*)(brow + (kt + 2) * 32);
            a2 = __builtin_amdgcn_mfma_f32_16x16x32_bf16(aHi[kt + 2], b2, a2, 0, 0, 0);
            a2 = __builtin_amdgcn_mfma_f32_16x16x32_bf16(aLo[kt + 2], b2, a2, 0, 0, 0);
            short8 b3 = *(const short8*)(brow + (kt + 3) * 32);
            a3 = __builtin_amdgcn_mfma_f32_16x16x32_bf16(aHi[kt + 3], b3, a3, 0, 0, 0);
            a3 = __builtin_amdgcn_mfma_f32_16x16x32_bf16(aLo[kt + 3], b3, a3, 0, 0, 0);
        }
        floatx4 acc = (a0 + a1) + (a2 + a3);

        // ---- in-lane epilogue: acc[r] = gate r pre-activation (H part) ----
        float xv  = xrow[t];
        float aIv = acc[0] + fmaf(xv, w0I, biasI);
        float aFv = acc[1] + fmaf(xv, w0F, biasF);
        float aCv = acc[2] + fmaf(xv, w0C, biasC);
        float aOv = acc[3] + fmaf(xv, w0O, biasO);
        float I  = fast_sigmoid(aIv);
        float F  = fast_sigmoid(aFv);
        float Ch = fast_tanh(aCv);
        Cst = fmaf(F, Cst, I * Ch);
        float Hn = aOv * fast_tanh(Cst);      // reference: O has NO sigmoid

        if (t < SEQ - 1) {
            // pack neighbor cols (q, q+1) into one 4-B coherent store
            int v = (int)f2bf(Hn);
            int o = __shfl_xor(v, 16);        // partner quad's bf16
            if ((q & 1) == 0) {
                unsigned val = (unsigned)(unsigned short)v |
                               ((unsigned)(unsigned short)o << 16);
                unsigned* dst = (unsigned*)(hb + ((t + 1) & 1) * SLOTU + g * GSLOTU
                                            + c * 512 + colD);   // colD even here
                __hip_atomic_store(dst, val, __ATOMIC_RELAXED, __HIP_MEMORY_SCOPE_AGENT);
            }
            __syncthreads();                  // barrier drains vmcnt(0) (tracked stores)
            if (tid == 0)
                __hip_atomic_store(myflag, t + 1, __ATOMIC_RELAXED, __HIP_MEMORY_SCOPE_AGENT);
        } else {
            int o = bD * HID + colD;
            out[o] = Hn; out[65536 + o] = Hn; out[131072 + o] = Cst;
        }
    }
}

extern "C" void kernel_launch(void* const* d_in, const int* in_sizes, int n_in,
                              void* d_out, int out_size, void* d_ws, size_t ws_size,
                              hipStream_t stream) {
    const float* x  = (const float*)d_in[0];
    const float* H0 = (const float*)d_in[1];
    const float* C0 = (const float*)d_in[2];
    const float* Wi = (const float*)d_in[3];
    const float* bi = (const float*)d_in[4];
    const float* Wf = (const float*)d_in[5];
    const float* bf = (const float*)d_in[6];
    const float* Wc = (const float*)d_in[7];
    const float* bc = (const float*)d_in[8];
    const float* Wo = (const float*)d_in[9];
    const float* bo = (const float*)d_in[10];
    float* out = (float*)d_out;
    unsigned short* hb = (unsigned short*)d_ws;   // 256 KB H slots + 2 KB flags

    const int init_elems = SLOTU + NGROUP * 64;
    hipLaunchKernelGGL(lstm_init, dim3((init_elems + 255) / 256), dim3(256), 0, stream,
                       H0, hb);
    hipLaunchKernelGGL(lstm_main, dim3(NGROUP * BPG), dim3(256), 0, stream,
                       x, C0, Wi, bi, Wf, bf, Wc, bc, Wo, bo, out, hb);
}

// Round 14
// 1335.847 us; speedup vs baseline: 1.0212x; 1.0212x over previous
//
#include <hip/hip_runtime.h>
#include <math.h>

#define SEQ 512
#define HID 512
#define NGROUP 8              // batch groups of 16; group g = bid & 7
#define GB 16                 // batches per group
#define BPG 32                // blocks per group (each owns 16 n-cols)
#define SLOTU 65536           // ushorts per H slot ([g][b16][k512] bf16)
#define GSLOTU 8192           // ushorts per group per slot (16 KB)
#define LROW 520              // LDS row stride in ushorts (512 + 8 pad -> balanced banks)
// ws layout: [0, 256 KB) two bf16 H slots | [256 KB, +2 KB) flags (8 groups * 64 ints)

typedef __attribute__((ext_vector_type(8))) short short8;   // 8 bf16 = 4 VGPRs (MFMA A/B)
typedef __attribute__((ext_vector_type(4))) float floatx4;  // MFMA C/D

__device__ __forceinline__ unsigned short f2bf(float f) {   // RNE fp32->bf16
    unsigned u = __builtin_bit_cast(unsigned, f);
    return (unsigned short)((u + 0x7FFFu + ((u >> 16) & 1u)) >> 16);
}
__device__ __forceinline__ float bf2f(unsigned short h) {
    unsigned u = ((unsigned)h) << 16;
    return __builtin_bit_cast(float, u);
}
__device__ __forceinline__ float fast_sigmoid(float x) {
    return 1.0f / (1.0f + __expf(-x));
}
__device__ __forceinline__ float fast_tanh(float x) {       // stable for |x| large
    float e = __expf(-2.0f * fabsf(x));
    float t = (1.0f - e) / (1.0f + e);
    return x < 0.0f ? -t : t;
}

__global__ void lstm_init(const float* __restrict__ H0, unsigned short* __restrict__ hb) {
    int idx = blockIdx.x * blockDim.x + threadIdx.x;
    if (idx < SLOTU) {
        int k = idx & 511, b = (idx >> 9) & 15, g = idx >> 13;
        hb[idx] = f2bf(H0[(g * GB + b) * HID + k]);       // slot0 = H(t=0)
    } else if (idx < SLOTU + NGROUP * 64) {
        ((int*)(hb + 2 * SLOTU))[idx - SLOTU] = 0;        // flags = 0
    }
}

__global__ __launch_bounds__(256, 1)
void lstm_main(const float* __restrict__ x,
               const float* __restrict__ C0,
               const float* __restrict__ Wi, const float* __restrict__ bi,
               const float* __restrict__ Wf, const float* __restrict__ bf_,
               const float* __restrict__ Wc, const float* __restrict__ bc,
               const float* __restrict__ Wo, const float* __restrict__ bo,
               float* __restrict__ out, unsigned short* __restrict__ hb) {
    int* flags = (int*)(hb + 2 * SLOTU);

    const int bid  = blockIdx.x;
    const int g    = bid & 7;
    const int cb   = bid >> 3;
    const int tid  = threadIdx.x;
    const int w    = tid >> 6;          // wave 0..3 (owns cols cb*16+w*4 .. +3)
    const int lane = tid & 63;
    const int q    = lane >> 4;         // quad
    const int c    = lane & 15;         // low lane bits

    // MFMA index roles (m89/m91/m120-verified layouts):
    //   A-frag: lane holds A[m = lane&15][k = quad*8+j]   (m = col_local*4 + gate)
    //   B-frag: lane holds B[k = quad*8+j][n = lane&15]   (n = batch)
    //   D:      lane holds D[m = quad*4+r][n = lane&15]   (r = gate, col_local = quad)
    const int gate = c & 3;                       // for A-frag build
    const int colA = cb * 16 + w * 4 + (c >> 2);  // A-frag column
    const int colD = cb * 16 + w * 4 + q;         // this lane's output column
    const int bD   = g * GB + c;                  // this lane's batch

    // ---- A-fragments: hi+lo bf16 split of W, step-invariant, in registers ----
    const float* Wg = (gate == 0) ? Wi : (gate == 1) ? Wf : (gate == 2) ? Wc : Wo;
    short8 aHi[16], aLo[16];
    #pragma unroll
    for (int kt = 0; kt < 16; ++kt) {
        #pragma unroll
        for (int j = 0; j < 8; ++j) {
            int k = kt * 32 + q * 8 + j;
            float wv = Wg[(k + 1) * HID + colA];   // rows 1..512 are H weights
            unsigned short hi = f2bf(wv);
            unsigned short lo = f2bf(wv - bf2f(hi));
            aHi[kt][j] = (short)hi;
            aLo[kt][j] = (short)lo;
        }
    }

    // epilogue constants (row 0 = x weight, bias) + C state, all for (colD, bD)
    const float biasI = bi[colD], biasF = bf_[colD], biasC = bc[colD], biasO = bo[colD];
    const float w0I = Wi[colD], w0F = Wf[colD], w0C = Wc[colD], w0O = Wo[colD];
    float Cst = C0[bD * HID + colD];
    const float* xrow = x + bD * SEQ;

    __shared__ unsigned short hlds[16 * LROW];   // 16.6 KB staged H tile [b][k] bf16

    int* myflag = flags + g * 64 + cb;

    for (int t = 0; t < SEQ; ++t) {
        // ---- wait for all 32 producer flags of this group (throttled poll;
        //      s_sleep(2) proven right: removing it cost +2.5% in r13) ----
        if (tid < BPG) {
            const int* fp = flags + g * 64 + tid;
            while (__hip_atomic_load(fp, __ATOMIC_RELAXED, __HIP_MEMORY_SCOPE_AGENT) < t)
                __builtin_amdgcn_s_sleep(2);
        }
        __syncthreads();

        // ---- stage 16 KB H_t tile: 64 B/thread, coherent dwordx4 burst ----
        {
            const unsigned short* gsrc = hb + (t & 1) * SLOTU + g * GSLOTU + tid * 32;
            float4 v0, v1, v2, v3;
            asm volatile(
                "global_load_dwordx4 %0, %4, off sc0 sc1\n\t"
                "global_load_dwordx4 %1, %4, off offset:16 sc0 sc1\n\t"
                "global_load_dwordx4 %2, %4, off offset:32 sc0 sc1\n\t"
                "global_load_dwordx4 %3, %4, off offset:48 sc0 sc1\n\t"
                "s_waitcnt vmcnt(0)"
                : "=&v"(v0), "=&v"(v1), "=&v"(v2), "=&v"(v3)
                : "v"(gsrc) : "memory");
            int b = tid >> 4, ch = tid & 15;
            unsigned short* dst = hlds + b * LROW + ch * 32;
            *(float4*)(dst + 0)  = v0;
            *(float4*)(dst + 8)  = v1;
            *(float4*)(dst + 16) = v2;
            *(float4*)(dst + 24) = v3;
        }
        __syncthreads();

        // ---- ISOLATED CHANGE vs r12: issue the epilogue's x-load BEFORE the
        //      GEMM so the ~400cy MFMA region hides its L2 latency (it was a
        //      serial dependent load between GEMM and activations). ----
        float xv = xrow[t];

        // ---- GEMM: D[64x16] = W^T (hi+lo) x H, 16 K-tiles, A in regs, B from LDS.
        //      4 independent accumulator chains (proven r12: -32 us vs single). ----
        floatx4 a0 = {0.f, 0.f, 0.f, 0.f}, a1 = a0, a2 = a0, a3 = a0;
        const unsigned short* brow = hlds + c * LROW + q * 8;
        #pragma unroll
        for (int kt = 0; kt < 16; kt += 4) {
            short8 b0 = *(const short8*)(brow + (kt + 0) * 32);
            a0 = __builtin_amdgcn_mfma_f32_16x16x32_bf16(aHi[kt + 0], b0, a0, 0, 0, 0);
            a0 = __builtin_amdgcn_mfma_f32_16x16x32_bf16(aLo[kt + 0], b0, a0, 0, 0, 0);
            short8 b1 = *(const short8*)(brow + (kt + 1) * 32);
            a1 = __builtin_amdgcn_mfma_f32_16x16x32_bf16(aHi[kt + 1], b1, a1, 0, 0, 0);
            a1 = __builtin_amdgcn_mfma_f32_16x16x32_bf16(aLo[kt + 1], b1, a1, 0, 0, 0);
            short8 b2 = *(const short8*)(brow + (kt + 2) * 32);
            a2 = __builtin_amdgcn_mfma_f32_16x16x32_bf16(aHi[kt + 2], b2, a2, 0, 0, 0);
            a2 = __builtin_amdgcn_mfma_f32_16x16x32_bf16(aLo[kt + 2], b2, a2, 0, 0, 0);
            short8 b3 = *(const short8*)(brow + (kt + 3) * 32);
            a3 = __builtin_amdgcn_mfma_f32_16x16x32_bf16(aHi[kt + 3], b3, a3, 0, 0, 0);
            a3 = __builtin_amdgcn_mfma_f32_16x16x32_bf16(aLo[kt + 3], b3, a3, 0, 0, 0);
        }
        floatx4 acc = (a0 + a1) + (a2 + a3);

        // ---- in-lane epilogue: acc[r] = gate r pre-activation (H part) ----
        float aIv = acc[0] + fmaf(xv, w0I, biasI);
        float aFv = acc[1] + fmaf(xv, w0F, biasF);
        float aCv = acc[2] + fmaf(xv, w0C, biasC);
        float aOv = acc[3] + fmaf(xv, w0O, biasO);
        float I  = fast_sigmoid(aIv);
        float F  = fast_sigmoid(aFv);
        float Ch = fast_tanh(aCv);
        Cst = fmaf(F, Cst, I * Ch);
        float Hn = aOv * fast_tanh(Cst);      // reference: O has NO sigmoid

        if (t < SEQ - 1) {
            // pack neighbor cols (q, q+1) into one 4-B coherent store
            int v = (int)f2bf(Hn);
            int o = __shfl_xor(v, 16);        // partner quad's bf16
            if ((q & 1) == 0) {
                unsigned val = (unsigned)(unsigned short)v |
                               ((unsigned)(unsigned short)o << 16);
                unsigned* dst = (unsigned*)(hb + ((t + 1) & 1) * SLOTU + g * GSLOTU
                                            + c * 512 + colD);   // colD even here
                __hip_atomic_store(dst, val, __ATOMIC_RELAXED, __HIP_MEMORY_SCOPE_AGENT);
            }
            __syncthreads();                  // barrier drains vmcnt(0) (tracked stores)
            if (tid == 0)
                __hip_atomic_store(myflag, t + 1, __ATOMIC_RELAXED, __HIP_MEMORY_SCOPE_AGENT);
        } else {
            int o = bD * HID + colD;
            out[o] = Hn; out[65536 + o] = Hn; out[131072 + o] = Cst;
        }
    }
}

extern "C" void kernel_launch(void* const* d_in, const int* in_sizes, int n_in,
                              void* d_out, int out_size, void* d_ws, size_t ws_size,
                              hipStream_t stream) {
    const float* x  = (const float*)d_in[0];
    const float* H0 = (const float*)d_in[1];
    const float* C0 = (const float*)d_in[2];
    const float* Wi = (const float*)d_in[3];
    const float* bi = (const float*)d_in[4];
    const float* Wf = (const float*)d_in[5];
    const float* bf = (const float*)d_in[6];
    const float* Wc = (const float*)d_in[7];
    const float* bc = (const float*)d_in[8];
    const float* Wo = (const float*)d_in[9];
    const float* bo = (const float*)d_in[10];
    float* out = (float*)d_out;
    unsigned short* hb = (unsigned short*)d_ws;   // 256 KB H slots + 2 KB flags

    const int init_elems = SLOTU + NGROUP * 64;
    hipLaunchKernelGGL(lstm_init, dim3((init_elems + 255) / 256), dim3(256), 0, stream,
                       H0, hb);
    hipLaunchKernelGGL(lstm_main, dim3(NGROUP * BPG), dim3(256), 0, stream,
                       x, C0, Wi, bi, Wf, bf, Wc, bc, Wo, bo, out, hb);
}